// Round 8
// baseline (10020.312 us; speedup 1.0000x reference)
//
#include <hip/hip_runtime.h>
#include <hip/hip_bf16.h>

// FPS (farthest point sampling) + gather for B=8, N=16384, C=256, m=N/4.
//
// Exactness: reference computes d = ((dx*dx + dy*dy) + dz*dz) with NO fma
// contraction; dist = min(dist, d); argmax takes the FIRST max index.
// Bit-exact replication validated absmax=0 in R2/R3/R4/R7.
//
// R8 change (argmax restructure; memory layout/protocol = R7, proven):
//  R7 counters: per-active-CU VALUBusy ~83% at 5392 cyc/iter => VALU-issue
//  saturated; the 3-op/pt argmax tracking + 7-op 'take' comparator stages
//  dominate. New scheme:
//   - inner loop: value-only (v_min dist update + v_max running max) 10/pt
//   - value reduce: fused-DPP fmaxf stages (1-2 VALU/stage, short chains)
//   - index recovery AFTER global max value gv is known: per j,
//     __ballot(dist[j]==gv); first nonzero ballot (ascending j) + ctz gives
//     the wave's min matching global index (strided ownership: g=j*1024+t,
//     (j,lane) lexicographic = g order within a wave); block stage = fused
//     v_min_i32 DPP reduce over per-wave candidates (INT_MAX if no match).
//  fmaxf over non-NaN all-+0.0 floats is order-independent => gv bit-exact;
//  equality set == reference argmax set; min index == first index.

constexpr int NPTS   = 16384;
constexpr int PTS    = 16;      // points per thread
constexpr int FPS_T  = 1024;    // threads per block
constexpr int WAVES  = FPS_T / 64;

template <int CTRL>
__device__ __forceinline__ float dpp_f(float x) {
    return __builtin_bit_cast(float,
        __builtin_amdgcn_update_dpp(0, __builtin_bit_cast(int, x), CTRL, 0xF, 0xF, true));
}
template <int CTRL>
__device__ __forceinline__ int dpp_i(int x) {
    return __builtin_amdgcn_update_dpp(0, x, CTRL, 0xF, 0xF, true);
}

// v_permlane16_swap_b32 a,b : per 32-lane half, a[16:31] <-> b[0:15].
// With a=b=v: neighbor(^16) = (lane&16) ? a' : b'.  Same for 32 with (lane&32).
__device__ __forceinline__ void permswap16_f(float &a, float &b) {
    asm volatile("v_permlane16_swap_b32 %0, %1" : "+v"(a), "+v"(b));
}
__device__ __forceinline__ void permswap32_f(float &a, float &b) {
    asm volatile("v_permlane32_swap_b32 %0, %1" : "+v"(a), "+v"(b));
}

__global__ __launch_bounds__(FPS_T)
__attribute__((amdgpu_waves_per_eu(4, 4)))
void fps_kernel(
    const float* __restrict__ pos,   // [B, N, 3]
    float* __restrict__ pos_out,     // [B, m, 3]
    int* __restrict__ idx_out,       // [B, m] in workspace
    int m)
{
    const int b    = blockIdx.x;
    const int t    = threadIdx.x;
    const int lane = t & 63;
    const int wid  = t >> 6;
    const bool l16 = (lane & 16) != 0;
    const bool l32 = (lane & 32) != 0;
    const float* posb = pos + (size_t)b * NPTS * 3;

    // small arrays FIRST: low LDS offsets (R5 regression: high-offset dynamic
    // indexing of these partials was the correctness culprit)
    __shared__ float  s_v[2][WAVES];
    __shared__ int    s_i[2][WAVES];
    __shared__ float2 sxy[NPTS];           // 128 KB: x,y per point

    // z + dist in registers; thread t owns points {j*1024 + t} (strided:
    // wave ds_read_b64 unit-stride => 2-way bank alias = free)
    float pz[PTS], dist[PTS];
#pragma unroll
    for (int j = 0; j < PTS; ++j) {
        const int i = j * FPS_T + t;
        sxy[i]  = make_float2(posb[i * 3 + 0], posb[i * 3 + 1]);  // self-staged
        pz[j]   = posb[i * 3 + 2];
        dist[j] = 1e10f;
    }

    float lx = posb[0], ly = posb[1], lz = posb[2];

    if (t == 0) {
        idx_out[(size_t)b * m] = 0;
        pos_out[((size_t)b * m) * 3 + 0] = lx;
        pos_out[((size_t)b * m) * 3 + 1] = ly;
        pos_out[((size_t)b * m) * 3 + 2] = lz;
    }
    __syncthreads();

    for (int s = 1; s < m; ++s) {
        // ---- distance update + value-only running max (10 VALU/pt) ----
        float bv = -1.0f;
        {
#pragma clang fp contract(off)
#pragma unroll
            for (int j = 0; j < PTS; ++j) {
                float2 xy = sxy[j * FPS_T + t];
                float dx = xy.x - lx;
                float dy = xy.y - ly;
                float dz = pz[j] - lz;
                float d  = ((dx * dx) + (dy * dy)) + (dz * dz);  // ref order, no fma
                float nd = fminf(dist[j], d);
                dist[j]  = nd;
                bv = fmaxf(bv, nd);
            }
        }

        // ---- wave value-max: fused-DPP stages ----
        bv = fmaxf(bv, dpp_f<0xB1>(bv));   // quad_perm ^1
        bv = fmaxf(bv, dpp_f<0x4E>(bv));   // quad_perm ^2
        bv = fmaxf(bv, dpp_f<0x141>(bv));  // half_mirror
        bv = fmaxf(bv, dpp_f<0x140>(bv));  // row_mirror
        { float a = bv, c = bv; permswap16_f(a, c); bv = fmaxf(bv, l16 ? a : c); }
        { float a = bv, c = bv; permswap32_f(a, c); bv = fmaxf(bv, l32 ? a : c); }

        // ---- exchange 1: per-wave max values (double-buffered, 1 barrier) ----
        const int buf = s & 1;
        if (lane == 0) s_v[buf][wid] = bv;
        __syncthreads();

        float gv = s_v[buf][lane & (WAVES - 1)];
        gv = fmaxf(gv, dpp_f<0xB1>(gv));
        gv = fmaxf(gv, dpp_f<0x4E>(gv));
        gv = fmaxf(gv, dpp_f<0x141>(gv));
        gv = fmaxf(gv, dpp_f<0x140>(gv));   // gv = global max value (all lanes)

        // ---- index recovery: first j with a match, lowest lane at that j ----
        int cand = 0x7FFFFFFF;              // wave-uniform scalar
#pragma unroll
        for (int j = 0; j < PTS; ++j) {
            unsigned long long mk = __ballot(dist[j] == gv);
            if (cand == 0x7FFFFFFF && mk != 0ull)
                cand = j * FPS_T + (wid << 6) + (int)__builtin_ctzll(mk);
        }

        // ---- exchange 2: per-wave candidate indices, min-index reduce ----
        if (lane == 0) s_i[buf][wid] = cand;
        __syncthreads();

        int gi = s_i[buf][lane & (WAVES - 1)];
        { int o = dpp_i<0xB1>(gi);  gi = o < gi ? o : gi; }
        { int o = dpp_i<0x4E>(gi);  gi = o < gi ? o : gi; }
        { int o = dpp_i<0x141>(gi); gi = o < gi ? o : gi; }
        { int o = dpp_i<0x140>(gi); gi = o < gi ? o : gi; }

        // winner coords via wave-uniform load (pos L2-resident, 192 KB/batch)
        int gis = __builtin_amdgcn_readfirstlane(gi);
        lx = posb[gis * 3 + 0];
        ly = posb[gis * 3 + 1];
        lz = posb[gis * 3 + 2];

        if (t == 0) {
            idx_out[(size_t)b * m + s] = gis;
            pos_out[((size_t)b * m + s) * 3 + 0] = lx;
            pos_out[((size_t)b * m + s) * 3 + 1] = ly;
            pos_out[((size_t)b * m + s) * 3 + 2] = lz;
        }
    }
}

// feat gather: one wave per output row, 256 floats = 64 lanes x float4
__global__ __launch_bounds__(256) void gather_kernel(
    const float* __restrict__ feat,   // [B, N, C]
    const int*   __restrict__ idx,    // [B, m]
    float*       __restrict__ out,    // [B, m, C]
    int m, int C)
{
    const int wid  = threadIdx.x >> 6;
    const int lane = threadIdx.x & 63;
    const int r    = blockIdx.x * 4 + wid;     // row in [0, B*m)
    const int b    = r >> 12;                  // m = 4096
    const int src  = idx[r];
    const float4* sp = (const float4*)(feat + ((size_t)b * NPTS + src) * C);
    float4*       dp = (float4*)(out + (size_t)r * C);
    dp[lane] = sp[lane];
}

extern "C" void kernel_launch(void* const* d_in, const int* in_sizes, int n_in,
                              void* d_out, int out_size, void* d_ws, size_t ws_size,
                              hipStream_t stream) {
    const float* pos  = (const float*)d_in[0];   // [8, 16384, 3] f32
    const float* feat = (const float*)d_in[1];   // [8, 16384, 256] f32

    const int B = 8, C = 256;
    const int m = NPTS / 4;                      // 4096

    float* out_pos  = (float*)d_out;                          // [8, 4096, 3]
    float* out_feat = out_pos + (size_t)B * m * 3;            // [8, 4096, 256]
    int*   idx      = (int*)d_ws;                             // [8, 4096] = 128 KB

    fps_kernel<<<dim3(B), dim3(FPS_T), 0, stream>>>(pos, out_pos, idx, m);
    gather_kernel<<<dim3(B * m / 4), dim3(256), 0, stream>>>(feat, idx, out_feat, m, C);
}